// Round 2
// baseline (1420.134 us; speedup 1.0000x reference)
//
#include <hip/hip_runtime.h>

#define VOCAB 33
#define EMBED 200
#define HIDDEN 200
#define BATCH 256
#define SEQ 1024

typedef float v2f __attribute__((ext_vector_type(2)));

// ---------------------------------------------------------------------------
// Kernel A: Ep[v][j] = sum_e embedding[v][e] * W_e[e][j]   (33 x 200 GEMM)
// Runs only when d_ws can hold Ep (26.4 KB). Otherwise rnn_kernel computes
// Ep per-block in LDS (no cross-block aliasing -> no dispatch-order races).
// ---------------------------------------------------------------------------
__global__ __launch_bounds__(256) void ep_kernel(const float* __restrict__ emb,
                                                 const float* __restrict__ We,
                                                 float* __restrict__ Ep) {
    const int v = blockIdx.x;     // 0..32
    const int j = threadIdx.x;    // 0..255
    if (j >= HIDDEN) return;
    float acc = 0.f;
    const float* er = emb + v * EMBED;
    for (int e = 0; e < EMBED; ++e)
        acc = fmaf(er[e], We[e * HIDDEN + j], acc);
    Ep[v * HIDDEN + j] = acc;
}

// ---------------------------------------------------------------------------
// Kernel B: per-batch-row RNN scan. One WG (256 thr) per batch row, ~one/CU.
//   - W_h column j register-resident (200 VGPR/thread)
//   - h double-buffered in LDS, broadcast float4 reads
//   - logits fused one step behind; W_o slice register-resident
//   - part[] double-buffered -> ONE barrier per step
// ---------------------------------------------------------------------------
__global__ __launch_bounds__(256, 1) void rnn_kernel(
    const int*   __restrict__ x,
    const float* __restrict__ hidden0,
    const float* __restrict__ Wh,
    const float* __restrict__ Wo,
    const float* __restrict__ Ep,      // may be nullptr -> compute in-block
    const float* __restrict__ emb,     // used only when Ep == nullptr
    const float* __restrict__ We,      // used only when Ep == nullptr
    float*       __restrict__ out)
{
    __shared__ float ep_s[VOCAB * HIDDEN];            // 26400 B
    __shared__ float emb_s[VOCAB * EMBED];            // 26400 B (init only)
    __shared__ __align__(16) float hbuf[2][224];      // 1792 B, k>=200 stays 0
    __shared__ float part[2][7][34];                  // 1904 B
    __shared__ int   xs[SEQ];                         // 4096 B

    const int b   = blockIdx.x;
    const int tid = threadIdx.x;
    const int j   = tid;                 // GEMV output role (j < 200 active)

    // --- Ep into LDS: load precomputed, or compute per-block ---
    if (Ep != nullptr) {
        for (int o = tid; o < VOCAB * HIDDEN; o += 256) ep_s[o] = Ep[o];
    } else {
        for (int o = tid; o < VOCAB * EMBED; o += 256) emb_s[o] = emb[o];
        __syncthreads();
        if (j < HIDDEN) {
            float acc[VOCAB];
            #pragma unroll
            for (int v = 0; v < VOCAB; ++v) acc[v] = 0.f;
            for (int e = 0; e < EMBED; ++e) {
                const float we = We[e * HIDDEN + j];
                #pragma unroll
                for (int v = 0; v < VOCAB; ++v)
                    acc[v] = fmaf(emb_s[v * EMBED + e], we, acc[v]);
            }
            #pragma unroll
            for (int v = 0; v < VOCAB; ++v) ep_s[v * HIDDEN + j] = acc[v];
        }
    }

    // --- stage x row, init h double-buffer ---
    for (int o = tid; o < SEQ; o += 256) xs[o] = x[b * SEQ + o];
    if (tid < 224) {
        hbuf[0][tid] = (tid < HIDDEN) ? hidden0[b * HIDDEN + tid] : 0.f;
        hbuf[1][tid] = 0.f;
    }

    // --- register-resident W_h column j (paired along k) ---
    v2f wcol[100];
    #pragma unroll
    for (int p = 0; p < 100; ++p) {
        if (j < HIDDEN) {
            wcol[p].x = Wh[(2 * p)     * HIDDEN + j];
            wcol[p].y = Wh[(2 * p + 1) * HIDDEN + j];
        } else {
            wcol[p].x = 0.f; wcol[p].y = 0.f;
        }
    }

    // --- logits role: v = tid % 33, kc = tid / 33 (kc < 7 active), k-chunk 32
    const int v  = tid % 33;
    const int kc = tid / 33;             // 0..7 ; kc==7 threads inactive
    const int hoff = (kc < 7) ? 32 * kc : 0;
    v2f wo[16];
    #pragma unroll
    for (int i = 0; i < 16; ++i) {
        const int k = 32 * kc + 2 * i;
        float a0 = (kc < 7 && k     < HIDDEN) ? Wo[k       * VOCAB + v] : 0.f;
        float a1 = (kc < 7 && k + 1 < HIDDEN) ? Wo[(k + 1) * VOCAB + v] : 0.f;
        wo[i].x = a0; wo[i].y = a1;
    }
    __syncthreads();

    const float LOG2E2 = 2.8853900817779268f;   // 2*log2(e)
    float* outb = out + (size_t)b * (SEQ * VOCAB);
    float* fh   = out + (size_t)BATCH * SEQ * VOCAB + (size_t)b * HIDDEN;

    for (int t = 0; t < SEQ; ++t) {
        const int p = t & 1;
        const float4* h4 = (const float4*)&hbuf[p][0];

        // ---- hidden GEMV: y_j = sum_k h[k] * Wh[k][j] ----
        v2f acc0 = {0.f, 0.f}, acc1 = {0.f, 0.f};
        v2f acc2 = {0.f, 0.f}, acc3 = {0.f, 0.f};
        #pragma unroll
        for (int q = 0; q < 50; q += 2) {
            float4 ha = h4[q];
            float4 hb = h4[q + 1];
            v2f h01 = {ha.x, ha.y}, h23 = {ha.z, ha.w};
            v2f h45 = {hb.x, hb.y}, h67 = {hb.z, hb.w};
            acc0 = __builtin_elementwise_fma(h01, wcol[2 * q],     acc0);
            acc1 = __builtin_elementwise_fma(h23, wcol[2 * q + 1], acc1);
            acc2 = __builtin_elementwise_fma(h45, wcol[2 * q + 2], acc2);
            acc3 = __builtin_elementwise_fma(h67, wcol[2 * q + 3], acc3);
        }

        // ---- logits partials for hbuf[p] (= h_{t-1}) ----
        const float4* h4l = (const float4*)&hbuf[p][hoff];
        v2f lac0 = {0.f, 0.f}, lac1 = {0.f, 0.f};
        #pragma unroll
        for (int q = 0; q < 8; ++q) {
            float4 hh = h4l[q];
            v2f p01 = {hh.x, hh.y}, p23 = {hh.z, hh.w};
            lac0 = __builtin_elementwise_fma(p01, wo[2 * q],     lac0);
            lac1 = __builtin_elementwise_fma(p23, wo[2 * q + 1], lac1);
        }

        // ---- h update: h_t = tanh(y + Ep[x_t]) via exp2 ----
        float y = (acc0.x + acc0.y) + (acc1.x + acc1.y)
                + (acc2.x + acc2.y) + (acc3.x + acc3.y);
        const int idx = xs[t];
        float z  = y + ((j < HIDDEN) ? ep_s[idx * HIDDEN + j] : 0.f);
        float e  = __builtin_amdgcn_exp2f(z * LOG2E2);
        float hn = (e - 1.f) * __builtin_amdgcn_rcpf(e + 1.f);

        if (kc < 7) part[p][kc][v] = (lac0.x + lac0.y) + (lac1.x + lac1.y);
        if (j < HIDDEN) hbuf[p ^ 1][j] = hn;
        __syncthreads();   // single barrier: part+hbuf double-buffered

        if (t > 0 && tid < VOCAB) {
            float s = part[p][0][tid] + part[p][1][tid] + part[p][2][tid]
                    + part[p][3][tid] + part[p][4][tid] + part[p][5][tid]
                    + part[p][6][tid];
            outb[(size_t)(t - 1) * VOCAB + tid] = s;
        }
    }

    // ---- epilogue: logits for t = SEQ-1 from hbuf[SEQ&1] + final hidden ----
    {
        const int pf = SEQ & 1;          // 0
        const float4* h4l = (const float4*)&hbuf[pf][hoff];
        v2f lac0 = {0.f, 0.f}, lac1 = {0.f, 0.f};
        #pragma unroll
        for (int q = 0; q < 8; ++q) {
            float4 hh = h4l[q];
            v2f p01 = {hh.x, hh.y}, p23 = {hh.z, hh.w};
            lac0 = __builtin_elementwise_fma(p01, wo[2 * q],     lac0);
            lac1 = __builtin_elementwise_fma(p23, wo[2 * q + 1], lac1);
        }
        if (kc < 7) part[pf][kc][v] = (lac0.x + lac0.y) + (lac1.x + lac1.y);
        __syncthreads();
        if (tid < VOCAB) {
            float s = part[pf][0][tid] + part[pf][1][tid] + part[pf][2][tid]
                    + part[pf][3][tid] + part[pf][4][tid] + part[pf][5][tid]
                    + part[pf][6][tid];
            outb[(size_t)(SEQ - 1) * VOCAB + tid] = s;
        }
        if (j < HIDDEN) fh[j] = hbuf[pf][j];
    }
}

// ---------------------------------------------------------------------------
extern "C" void kernel_launch(void* const* d_in, const int* in_sizes, int n_in,
                              void* d_out, int out_size, void* d_ws, size_t ws_size,
                              hipStream_t stream) {
    const int*   x   = (const int*)  d_in[0];
    const float* h0  = (const float*)d_in[1];
    const float* emb = (const float*)d_in[2];
    const float* We  = (const float*)d_in[3];
    const float* Wh  = (const float*)d_in[4];
    const float* Wo  = (const float*)d_in[5];
    float* out = (float*)d_out;

    const size_t ep_bytes = (size_t)VOCAB * HIDDEN * sizeof(float);
    float* ep = (ws_size >= ep_bytes) ? (float*)d_ws : nullptr;

    if (ep) ep_kernel<<<VOCAB, 256, 0, stream>>>(emb, We, ep);
    rnn_kernel<<<BATCH, 256, 0, stream>>>(x, h0, Wh, Wo, ep, emb, We, out);
}

// Round 3
// 774.508 us; speedup vs baseline: 1.8336x; 1.8336x over previous
//
#include <hip/hip_runtime.h>

#define VOCAB 33
#define EMBED 200
#define HIDDEN 200
#define BATCH 256
#define SEQ 1024
#define KW 50               // k-slice per wave
#define NW 4                // waves per block

typedef float v2f __attribute__((ext_vector_type(2)));

// ---------------------------------------------------------------------------
// Kernel A: Ep[v][j] = sum_e embedding[v][e] * W_e[e][j]   (33 x 200 GEMM)
// ---------------------------------------------------------------------------
__global__ __launch_bounds__(256) void ep_kernel(const float* __restrict__ emb,
                                                 const float* __restrict__ We,
                                                 float* __restrict__ Ep) {
    const int v = blockIdx.x;     // 0..32
    const int j = threadIdx.x;    // 0..255
    if (j >= HIDDEN) return;
    float acc = 0.f;
    const float* er = emb + v * EMBED;
    for (int e = 0; e < EMBED; ++e)
        acc = fmaf(er[e], We[e * HIDDEN + j], acc);
    Ep[v * HIDDEN + j] = acc;
}

// ---------------------------------------------------------------------------
// Kernel B: per-batch-row RNN scan, k-split across 4 waves.
//   - wave w owns k in [50w, 50w+50); lane l owns output slots {l,64+l,128+l,192+l}
//   - W slice register-resident (200 VGPR); slot3 doubles as W_o columns
//     (lanes 8..40 -> logit columns v=0..32, partial slots 200..232)
//   - h[50w+l] lives in lane l's register; broadcast via v_readlane -> SGPR FMA
//   - inner k-loop has ZERO LDS instructions
//   - one barrier per step; partial buffer double-buffered by t&1
// ---------------------------------------------------------------------------
__global__ __launch_bounds__(256, 1) void rnn_kernel(
    const int*   __restrict__ x,
    const float* __restrict__ hidden0,
    const float* __restrict__ Wh,
    const float* __restrict__ Wo,
    const float* __restrict__ Ep,      // may be nullptr -> compute in-block
    const float* __restrict__ emb,     // used only when Ep == nullptr
    const float* __restrict__ We,      // used only when Ep == nullptr
    float*       __restrict__ out)
{
    __shared__ float ep_s[VOCAB * HIDDEN];       // 26400 B (also emb staging)
    __shared__ float part[2][NW][256];           // 8192 B
    __shared__ int   xs[SEQ];                    // 4096 B

    const int b   = blockIdx.x;
    const int tid = threadIdx.x;
    const int w   = tid >> 6;        // wave 0..3
    const int l   = tid & 63;        // lane 0..63
    const int k0  = w * KW;          // wave's k-slice base

    // --- Ep into LDS: load precomputed, or compute per-block ---
    if (Ep != nullptr) {
        for (int o = tid; o < VOCAB * HIDDEN; o += 256) ep_s[o] = Ep[o];
    } else {
        // stage emb (same 33x200 size) into ep_s, compute, overwrite
        for (int o = tid; o < VOCAB * EMBED; o += 256) ep_s[o] = emb[o];
        __syncthreads();
        float acc[VOCAB];
        if (tid < HIDDEN) {
            #pragma unroll
            for (int v = 0; v < VOCAB; ++v) acc[v] = 0.f;
            for (int e = 0; e < EMBED; ++e) {
                const float we = We[e * HIDDEN + tid];
                #pragma unroll
                for (int v = 0; v < VOCAB; ++v)
                    acc[v] = fmaf(ep_s[v * EMBED + e], we, acc[v]);
            }
        }
        __syncthreads();
        if (tid < HIDDEN) {
            #pragma unroll
            for (int v = 0; v < VOCAB; ++v) ep_s[v * HIDDEN + tid] = acc[v];
        }
    }

    // --- stage x row ---
    for (int o = tid; o < SEQ; o += 256) xs[o] = x[b * SEQ + o];

    // --- register-resident W slice: wA = slots {l, 64+l}, wB = {128+l, slot3}
    // slot3: l<8 -> Wh col 192+l ; 8<=l<41 -> Wo col (l-8) ; else zero
    v2f wA[KW], wB[KW];
    #pragma unroll
    for (int k = 0; k < KW; ++k) {
        const int kr = k0 + k;
        wA[k].x = Wh[kr * HIDDEN + l];
        wA[k].y = Wh[kr * HIDDEN + 64 + l];
        wB[k].x = Wh[kr * HIDDEN + 128 + l];
        wB[k].y = (l < 8)  ? Wh[kr * HIDDEN + 192 + l]
                : (l < 41) ? Wo[kr * VOCAB + (l - 8)]
                           : 0.f;
    }

    // --- per-lane h: lane l (<50) of wave w holds h[50w + l] ---
    float vh = (l < KW) ? hidden0[b * HIDDEN + k0 + l] : 0.f;

    __syncthreads();

    const float LOG2E2 = 2.8853900817779268f;   // 2*log2(e)
    float* outb = out + (size_t)b * (SEQ * VOCAB);
    float* fh   = out + (size_t)BATCH * SEQ * VOCAB + (size_t)b * HIDDEN;

    const int vid = w * 14 + (l - 50);          // logit-reduce role (l>=50)

    int idx = xs[0];
    for (int t = 0; t < SEQ; ++t) {
        const int par = t & 1;

        // prefetch: ep value (used after barrier) + next idx
        float epv = (l < KW) ? ep_s[idx * HIDDEN + k0 + l] : 0.f;
        const int idx_n = (t + 1 < SEQ) ? xs[t + 1] : 0;

        // ---- k-loop: pure readlane + packed FMA, no LDS ----
        v2f accA = {0.f, 0.f}, accB = {0.f, 0.f};
        #pragma unroll
        for (int k = 0; k < KW; ++k) {
            const float hf =
                __int_as_float(__builtin_amdgcn_readlane(__float_as_int(vh), k));
            const v2f hh = {hf, hf};
            accA = __builtin_elementwise_fma(hh, wA[k], accA);
            accB = __builtin_elementwise_fma(hh, wB[k], accB);
        }

        // ---- write partials (conflict-free, lanes consecutive) ----
        part[par][w][l]       = accA.x;
        part[par][w][64 + l]  = accA.y;
        part[par][w][128 + l] = accB.x;
        part[par][w][192 + l] = accB.y;
        __syncthreads();

        // ---- reduce ----
        if (l < KW) {
            const int j = k0 + l;
            float s = part[par][0][j] + part[par][1][j]
                    + part[par][2][j] + part[par][3][j];
            float z  = s + epv;
            float e  = __builtin_amdgcn_exp2f(z * LOG2E2);
            vh = (e - 1.f) * __builtin_amdgcn_rcpf(e + 1.f);
        } else if (vid < VOCAB && t > 0) {
            const int c = 200 + vid;
            float s = part[par][0][c] + part[par][1][c]
                    + part[par][2][c] + part[par][3][c];
            outb[(size_t)(t - 1) * VOCAB + vid] = s;
        }
        idx = idx_n;
    }

    // ---- epilogue: logits of the final state h_SEQ ----
    {
        v2f accB = {0.f, 0.f};
        #pragma unroll
        for (int k = 0; k < KW; ++k) {
            const float hf =
                __int_as_float(__builtin_amdgcn_readlane(__float_as_int(vh), k));
            const v2f hh = {hf, hf};
            accB = __builtin_elementwise_fma(hh, wB[k], accB);
        }
        part[0][w][192 + l] = accB.y;
        __syncthreads();
        if (l >= KW && vid < VOCAB) {
            const int c = 200 + vid;
            float s = part[0][0][c] + part[0][1][c]
                    + part[0][2][c] + part[0][3][c];
            outb[(size_t)(SEQ - 1) * VOCAB + vid] = s;
        }
        if (l < KW) fh[k0 + l] = vh;
    }
}

// ---------------------------------------------------------------------------
extern "C" void kernel_launch(void* const* d_in, const int* in_sizes, int n_in,
                              void* d_out, int out_size, void* d_ws, size_t ws_size,
                              hipStream_t stream) {
    const int*   x   = (const int*)  d_in[0];
    const float* h0  = (const float*)d_in[1];
    const float* emb = (const float*)d_in[2];
    const float* We  = (const float*)d_in[3];
    const float* Wh  = (const float*)d_in[4];
    const float* Wo  = (const float*)d_in[5];
    float* out = (float*)d_out;

    const size_t ep_bytes = (size_t)VOCAB * HIDDEN * sizeof(float);
    float* ep = (ws_size >= ep_bytes) ? (float*)d_ws : nullptr;

    if (ep) ep_kernel<<<VOCAB, 256, 0, stream>>>(emb, We, ep);
    rnn_kernel<<<BATCH, 256, 0, stream>>>(x, h0, Wh, Wo, ep, emb, We, out);
}

// Round 4
// 681.178 us; speedup vs baseline: 2.0848x; 1.1370x over previous
//
#include <hip/hip_runtime.h>

#define VOCAB 33
#define EMBED 200
#define HIDDEN 200
#define BATCH 256
#define SEQ 1024
#define KW 50               // k-slice per wave
#define NW 4                // waves per block

typedef _Float16 h2 __attribute__((ext_vector_type(2)));

static __device__ __forceinline__ float fdot2f(h2 a, h2 b, float c) {
#if __has_builtin(__builtin_amdgcn_fdot2)
    return __builtin_amdgcn_fdot2(a, b, c, false);
#else
    return fmaf((float)a.x, (float)b.x, fmaf((float)a.y, (float)b.y, c));
#endif
}

// ---------------------------------------------------------------------------
// Kernel A: Ep[v][j] = sum_e embedding[v][e] * W_e[e][j]   (33 x 200 GEMM)
// ---------------------------------------------------------------------------
__global__ __launch_bounds__(256) void ep_kernel(const float* __restrict__ emb,
                                                 const float* __restrict__ We,
                                                 float* __restrict__ Ep) {
    const int v = blockIdx.x;     // 0..32
    const int j = threadIdx.x;    // 0..255
    if (j >= HIDDEN) return;
    float acc = 0.f;
    const float* er = emb + v * EMBED;
    for (int e = 0; e < EMBED; ++e)
        acc = fmaf(er[e], We[e * HIDDEN + j], acc);
    Ep[v * HIDDEN + j] = acc;
}

// ---------------------------------------------------------------------------
// Kernel B: per-batch-row RNN scan, k-split across 4 waves, f16 dot2 math.
//   - wave w owns k in [50w,50w+50) as 25 f16x2 pairs
//   - lane l owns output cols {l,64+l,128+l,192+l}; 100 f16x2 weight VGPRs
//   - slot3 cols 192..255: l<8 -> Wh col 192+l ; 8<=l<41 -> Wo col l-8
//   - h pair (h[k0+2l],h[k0+2l+1]) packed f16x2 in lane l<25; broadcast via
//     readlane -> v_dot2_f32_f16 (f32 accumulate). Zero LDS in k-loop.
//   - one barrier per step; part[] double-buffered
// ---------------------------------------------------------------------------
__global__ __launch_bounds__(256, 1) void rnn_kernel(
    const int*   __restrict__ x,
    const float* __restrict__ hidden0,
    const float* __restrict__ Wh,
    const float* __restrict__ Wo,
    const float* __restrict__ Ep,      // may be nullptr -> compute in-block
    const float* __restrict__ emb,     // used only when Ep == nullptr
    const float* __restrict__ We,      // used only when Ep == nullptr
    float*       __restrict__ out)
{
    __shared__ float ep_s[VOCAB * HIDDEN];       // 26400 B (also emb staging)
    __shared__ float part[2][NW][256];           // 8192 B
    __shared__ int   xs[SEQ];                    // 4096 B

    const int b   = blockIdx.x;
    const int tid = threadIdx.x;
    const int w   = tid >> 6;        // wave 0..3
    const int l   = tid & 63;        // lane 0..63
    const int k0  = w * KW;          // wave's k-slice base

    // --- Ep into LDS: load precomputed, or compute per-block ---
    if (Ep != nullptr) {
        for (int o = tid; o < VOCAB * HIDDEN; o += 256) ep_s[o] = Ep[o];
    } else {
        for (int o = tid; o < VOCAB * EMBED; o += 256) ep_s[o] = emb[o];
        __syncthreads();
        float acc[VOCAB];
        if (tid < HIDDEN) {
            #pragma unroll
            for (int v = 0; v < VOCAB; ++v) acc[v] = 0.f;
            for (int e = 0; e < EMBED; ++e) {
                const float we = We[e * HIDDEN + tid];
                #pragma unroll
                for (int v = 0; v < VOCAB; ++v)
                    acc[v] = fmaf(ep_s[v * EMBED + e], we, acc[v]);
            }
        }
        __syncthreads();
        if (tid < HIDDEN) {
            #pragma unroll
            for (int v = 0; v < VOCAB; ++v) ep_s[v * HIDDEN + tid] = acc[v];
        }
    }

    // --- stage x row ---
    for (int o = tid; o < SEQ; o += 256) xs[o] = x[b * SEQ + o];

    // --- register-resident W slice, f16x2 packed along k pairs ---
    h2 w0[25], w1[25], w2[25], w3[25];
    #pragma unroll
    for (int p = 0; p < 25; ++p) {
        const int kr = k0 + 2 * p;
        const float* r0 = Wh + (size_t)kr * HIDDEN;
        const float* r1 = r0 + HIDDEN;
        w0[p] = h2{(_Float16)r0[l],        (_Float16)r1[l]};
        w1[p] = h2{(_Float16)r0[64 + l],   (_Float16)r1[64 + l]};
        w2[p] = h2{(_Float16)r0[128 + l],  (_Float16)r1[128 + l]};
        float b0, b1;
        if (l < 8)       { b0 = r0[192 + l];              b1 = r1[192 + l]; }
        else if (l < 41) { b0 = Wo[kr * VOCAB + (l - 8)]; b1 = Wo[(kr + 1) * VOCAB + (l - 8)]; }
        else             { b0 = 0.f;                      b1 = 0.f; }
        w3[p] = h2{(_Float16)b0, (_Float16)b1};
    }

    // --- per-lane packed h pair: lane l<25 of wave w holds h[k0+2l..2l+1] ---
    float hn0 = 0.f, hn1 = 0.f;
    int hpi = 0;
    if (l < 25) {
        hn0 = hidden0[b * HIDDEN + k0 + 2 * l];
        hn1 = hidden0[b * HIDDEN + k0 + 2 * l + 1];
        hpi = __builtin_bit_cast(int, __builtin_amdgcn_cvt_pkrtz(hn0, hn1));
    }
    __syncthreads();

    const float LOG2E2 = 2.8853900817779268f;   // 2*log2(e)
    float* outb = out + (size_t)b * (SEQ * VOCAB);
    float* fh   = out + (size_t)BATCH * SEQ * VOCAB + (size_t)b * HIDDEN;
    const int vid = w * 14 + (l - 50);          // logit-reduce role (l>=50)

    int idx = xs[0];
    for (int t = 0; t < SEQ; ++t) {
        const int par = t & 1;

        // prefetch ep pair (consumed after barrier) + next idx
        float ep0 = 0.f, ep1 = 0.f;
        if (l < 25) {
            const float2 ev = *(const float2*)&ep_s[idx * HIDDEN + k0 + 2 * l];
            ep0 = ev.x; ep1 = ev.y;
        }
        const int idx_n = (t + 1 < SEQ) ? xs[t + 1] : 0;

        // ---- k-loop: 25 readlane + 100 dot2, zero LDS ----
        float a0 = 0.f, a1 = 0.f, a2 = 0.f, a3 = 0.f;
        #pragma unroll
        for (int p = 0; p < 25; ++p) {
            const h2 hh = __builtin_bit_cast(h2,
                              __builtin_amdgcn_readlane(hpi, p));
            a0 = fdot2f(hh, w0[p], a0);
            a1 = fdot2f(hh, w1[p], a1);
            a2 = fdot2f(hh, w2[p], a2);
            a3 = fdot2f(hh, w3[p], a3);
        }

        // ---- write partials (lanes consecutive -> conflict-free) ----
        part[par][w][l]       = a0;
        part[par][w][64 + l]  = a1;
        part[par][w][128 + l] = a2;
        part[par][w][192 + l] = a3;
        __syncthreads();

        // ---- reduce: lanes <25 produce the packed h pair; lanes >=50 logits
        if (l < 25) {
            const int j = k0 + 2 * l;
            const float2 p0 = *(const float2*)&part[par][0][j];
            const float2 p1 = *(const float2*)&part[par][1][j];
            const float2 p2 = *(const float2*)&part[par][2][j];
            const float2 p3 = *(const float2*)&part[par][3][j];
            const float z0 = (p0.x + p1.x) + (p2.x + p3.x) + ep0;
            const float z1 = (p0.y + p1.y) + (p2.y + p3.y) + ep1;
            const float e0 = __builtin_amdgcn_exp2f(z0 * LOG2E2);
            const float e1 = __builtin_amdgcn_exp2f(z1 * LOG2E2);
            hn0 = (e0 - 1.f) * __builtin_amdgcn_rcpf(e0 + 1.f);
            hn1 = (e1 - 1.f) * __builtin_amdgcn_rcpf(e1 + 1.f);
            hpi = __builtin_bit_cast(int, __builtin_amdgcn_cvt_pkrtz(hn0, hn1));
        } else if (l >= 50 && vid < VOCAB && t > 0) {
            const int c = 200 + vid;
            const float s = part[par][0][c] + part[par][1][c]
                          + part[par][2][c] + part[par][3][c];
            outb[(size_t)(t - 1) * VOCAB + vid] = s;
        }
        idx = idx_n;
    }

    // ---- epilogue: logits of final state + final hidden ----
    {
        float a3 = 0.f;
        #pragma unroll
        for (int p = 0; p < 25; ++p) {
            const h2 hh = __builtin_bit_cast(h2,
                              __builtin_amdgcn_readlane(hpi, p));
            a3 = fdot2f(hh, w3[p], a3);
        }
        part[0][w][192 + l] = a3;
        __syncthreads();
        if (l >= 50 && vid < VOCAB) {
            const int c = 200 + vid;
            const float s = part[0][0][c] + part[0][1][c]
                          + part[0][2][c] + part[0][3][c];
            outb[(size_t)(SEQ - 1) * VOCAB + vid] = s;
        }
        if (l < 25) {
            fh[k0 + 2 * l]     = hn0;
            fh[k0 + 2 * l + 1] = hn1;
        }
    }
}

// ---------------------------------------------------------------------------
extern "C" void kernel_launch(void* const* d_in, const int* in_sizes, int n_in,
                              void* d_out, int out_size, void* d_ws, size_t ws_size,
                              hipStream_t stream) {
    const int*   x   = (const int*)  d_in[0];
    const float* h0  = (const float*)d_in[1];
    const float* emb = (const float*)d_in[2];
    const float* We  = (const float*)d_in[3];
    const float* Wh  = (const float*)d_in[4];
    const float* Wo  = (const float*)d_in[5];
    float* out = (float*)d_out;

    const size_t ep_bytes = (size_t)VOCAB * HIDDEN * sizeof(float);
    float* ep = (ws_size >= ep_bytes) ? (float*)d_ws : nullptr;

    if (ep) ep_kernel<<<VOCAB, 256, 0, stream>>>(emb, We, ep);
    rnn_kernel<<<BATCH, 256, 0, stream>>>(x, h0, Wh, Wo, ep, emb, We, out);
}